// Round 9
// baseline (149.650 us; speedup 1.0000x reference)
//
#include <hip/hip_runtime.h>
#include <stdint.h>

#define Mdim 4096
#define Kdim 4096
#define Ndim 4096

typedef __attribute__((ext_vector_type(8))) short bf16x8;   // 8 bf16 (MFMA A/B frag)
typedef __attribute__((ext_vector_type(4))) float f32x4;    // 16x16 MFMA C/D frag

static __device__ __forceinline__ unsigned short f2bf_rne(float f) {
    union { float f; unsigned u; } v; v.f = f;
    unsigned u = v.u;
    u += 0x7FFFu + ((u >> 16) & 1u);
    return (unsigned short)(u >> 16);
}

static __device__ __forceinline__ void gload_lds16(const unsigned short* g, unsigned short* l) {
    __builtin_amdgcn_global_load_lds(
        (const __attribute__((address_space(1))) unsigned int*)g,
        (__attribute__((address_space(3))) unsigned int*)l,
        16, 0, 0);
}

#define BAR()   do { asm volatile("" ::: "memory"); __builtin_amdgcn_s_barrier(); asm volatile("" ::: "memory"); } while (0)
#define VMC(N)  asm volatile("s_waitcnt vmcnt(" #N ")" ::: "memory")
#define LGK0()  do { asm volatile("s_waitcnt lgkmcnt(0)" ::: "memory"); __builtin_amdgcn_sched_barrier(0); } while (0)
#define LGK8()  asm volatile("s_waitcnt lgkmcnt(8)" ::: "memory")

// ---------------------------------------------------------------------------
// Packing kernels: f32 -> bf16, k-major 16B-unit layout.
// A_p[(kt*8+o)*4096 + row] = A[row][kt*64+o*8 .. +8]
// B_p[(kt*8+o)*4096 + col] = B[kt*64+o*8 .. +8][col]   (B^T, k-major)
// ---------------------------------------------------------------------------
__global__ void conv_a_pack(const float* __restrict__ a, unsigned short* __restrict__ out) {
    __shared__ float tile[64][65];
    const int kt = blockIdx.x, rt = blockIdx.y;
    for (int i = threadIdx.x; i < 64 * 64; i += 256) {
        int r = i >> 6, c = i & 63;
        tile[r][c] = a[(size_t)(rt * 64 + r) * Kdim + kt * 64 + c];
    }
    __syncthreads();
    for (int i = threadIdx.x; i < 512; i += 256) {
        int o = i >> 6, r = i & 63;
        bf16x8 v;
#pragma unroll
        for (int e = 0; e < 8; ++e) v[e] = (short)f2bf_rne(tile[r][o * 8 + e]);
        ((bf16x8*)out)[(size_t)(kt * 8 + o) * 4096 + rt * 64 + r] = v;
    }
}

__global__ void conv_b_pack(const float* __restrict__ b, unsigned short* __restrict__ out) {
    __shared__ float tile[64][65];
    const int kt = blockIdx.x, nt = blockIdx.y;
    for (int i = threadIdx.x; i < 64 * 64; i += 256) {
        int kk = i >> 6, n = i & 63;
        tile[kk][n] = b[(size_t)(kt * 64 + kk) * Ndim + nt * 64 + n];
    }
    __syncthreads();
    for (int i = threadIdx.x; i < 512; i += 256) {
        int o = i >> 6, n = i & 63;
        bf16x8 v;
#pragma unroll
        for (int e = 0; e < 8; ++e) v[e] = (short)f2bf_rne(tile[o * 8 + e][n]);
        ((bf16x8*)out)[(size_t)(kt * 8 + o) * 4096 + nt * 64 + n] = v;
    }
}

// ---------------------------------------------------------------------------
// 256x256 bf16 GEMM, 16x16x32 MFMA, m201 8-phase schedule + k-major LDS.
// 512 thr = 8 waves (2M x 4N); per-wave 128x64 = acc[8][4] f32x4.
// LDS 128 KiB: buf(2) x [A: 2 halves x 16KB | B: 2 halves x 16KB].
// Half layout (k-major): 8 slabs (k-octets) x 128 packed rows x 16B.
//   A half mh: packed p = wm*64 + (m*16+fr)  <-> logical row wm*128+mh*64+...
//   B half nh: packed p = wn*32 + n'*16 + fr <-> logical col wn*64+nh*32+...
// Fragment ds_read_b128: 16-lane quarter reads 16 consecutive p = 256
// contiguous bytes -> conflict-free (r7-verified, SQ_LDS_BANK_CONFLICT=0).
// Staging: block-linear gload_lds direct from the k-major packed arrays.
//
// Phases per iteration (tiles t=buf0, t+1=buf1); reads are for the CURRENT
// phase's quadrant; stage 1 half per phase; vmcnt(6) only at ph4/ph8:
//  ph1: rd A0,B0(P0) 12 | stg A1(t+1)->b1 | lgk8 | BAR lgk0 Q(0,0) BAR
//  ph2: rd B1(P0)    4  | stg A0(t+2)->b0 |        BAR lgk0 Q(0,1) BAR
//  ph3: rd A1(P0)    8  | stg B0(t+2)->b0 |        BAR lgk0 Q(1,1) BAR
//  ph4:                 | stg B1(t+2)->b0 |        BAR      Q(1,0) VMC(6) BAR
//  ph5-8: mirror on P1, stages A1(t+2)->b0, {A0,B0,B1}(t+3)->b1, VMC(6)@ph8.
// Retire induction: at each VMC(6) exactly the 4 halves the next 4 phases
// read are retired (verified across iterations; prologue 7 halves + VMC(6);
// epilogue VMC(0) at ph4). WAR: each stage lands >=1 barrier after the
// last-read phase of the half it overwrites.
// ---------------------------------------------------------------------------
__global__ __launch_bounds__(512, 2) void gemm8k(const unsigned short* __restrict__ Ap,
                                                 const unsigned short* __restrict__ Bp,
                                                 float* __restrict__ C) {
    __shared__ unsigned short lds[65536];  // 128 KiB

    const int lane = threadIdx.x & 63;
    const int w    = threadIdx.x >> 6;   // 0..7
    const int wm   = w >> 2;             // 0..1
    const int wn   = w & 3;              // 0..3

    // bijective XCD swizzle (gridDim.x = 256)
    const int nch = gridDim.x >> 3;
    const int swz = (blockIdx.x & 7) * nch + (blockIdx.x >> 3);
    const int bm  = swz >> 4;
    const int bn  = swz & 15;

    // ---- staging geometry: wave w, instr j covers slab s_j, p = par*64+lane ----
    const int par = w & 1;
    const int s0  = w >> 1;              // j=0 slab; j=1 slab = s0+4
    const int aB  = bm * 256 + par * 128 + lane;                          // + MH*64
    const int bB  = bn * 256 + (par * 2 + (lane >> 5)) * 64 + (lane & 31); // + NH*32

#define STG_A(Q, MH, T) do {                                                     \
        unsigned short* d_ = lds + (Q) * 32768 + (MH) * 8192 + w * 512;          \
        gload_lds16(Ap + 8 * ((size_t)(T) * 32768 + s0 * 4096 + aB + (MH) * 64), \
                    d_);                                                         \
        gload_lds16(Ap + 8 * ((size_t)(T) * 32768 + (s0 + 4) * 4096 + aB + (MH) * 64), \
                    d_ + 4096);                                                  \
    } while (0)
#define STG_B(Q, NH, T) do {                                                     \
        unsigned short* d_ = lds + (Q) * 32768 + 16384 + (NH) * 8192 + w * 512;  \
        gload_lds16(Bp + 8 * ((size_t)(T) * 32768 + s0 * 4096 + bB + (NH) * 32), \
                    d_);                                                         \
        gload_lds16(Bp + 8 * ((size_t)(T) * 32768 + (s0 + 4) * 4096 + bB + (NH) * 32), \
                    d_ + 4096);                                                  \
    } while (0)

    // ---- fragment reads: addr = P*64K + [A: MH*16K | B: 32K+NH*16K]
    //      + (kk*4+hi)*2048 + p*16 ----
    const int fr = lane & 15;
    const int hi = lane >> 4;
    const char* ldsc = (const char*)lds;
    const int rdA = (wm * 64 + fr) * 16 + hi * 2048;   // + m*256 + kk*8192
    const int rdB = (wn * 32 + fr) * 16 + hi * 2048;   // + n'*256 + kk*8192

#define RD_A(DST, P, MH) do { _Pragma("unroll")                                  \
        for (int m_ = 0; m_ < 4; ++m_) {                                         \
            DST[m_][0] = *(const bf16x8*)(ldsc + (P) * 65536 + (MH) * 16384 +    \
                                          rdA + m_ * 256);                       \
            DST[m_][1] = *(const bf16x8*)(ldsc + (P) * 65536 + (MH) * 16384 +    \
                                          rdA + m_ * 256 + 8192);                \
        } } while (0)
#define RD_B(DST, P, NH) do { _Pragma("unroll")                                  \
        for (int n_ = 0; n_ < 2; ++n_) {                                         \
            DST[n_][0] = *(const bf16x8*)(ldsc + (P) * 65536 + 32768 +           \
                                          (NH) * 16384 + rdB + n_ * 256);        \
            DST[n_][1] = *(const bf16x8*)(ldsc + (P) * 65536 + 32768 +           \
                                          (NH) * 16384 + rdB + n_ * 256 + 8192); \
        } } while (0)

#define MM(MH, NH, AF, BF) do {                                                  \
        __builtin_amdgcn_s_setprio(1);                                           \
        _Pragma("unroll")                                                        \
        for (int m_ = 0; m_ < 4; ++m_)                                           \
            _Pragma("unroll")                                                    \
            for (int n_ = 0; n_ < 2; ++n_) {                                     \
                acc[(MH)*4 + m_][(NH)*2 + n_] = __builtin_amdgcn_mfma_f32_16x16x32_bf16( \
                    AF[m_][0], BF[n_][0], acc[(MH)*4 + m_][(NH)*2 + n_], 0, 0, 0); \
                acc[(MH)*4 + m_][(NH)*2 + n_] = __builtin_amdgcn_mfma_f32_16x16x32_bf16( \
                    AF[m_][1], BF[n_][1], acc[(MH)*4 + m_][(NH)*2 + n_], 0, 0, 0); \
            }                                                                    \
        __builtin_amdgcn_s_setprio(0);                                           \
    } while (0)

    f32x4 acc[8][4] = {};
    bf16x8 aX[4][2], aY[4][2], bX[2][2], bY[2][2];

    // ---- prologue: buf0(tile0) 4 halves + buf1(tile1) 3 halves; retire t0 ----
    STG_A(0, 0, 0); STG_B(0, 0, 0); STG_B(0, 1, 0); STG_A(0, 1, 0);
    STG_A(1, 0, 1); STG_B(1, 0, 1); STG_B(1, 1, 1);
    VMC(6);  // 3 halves outstanding -> all of tile 0 landed
    BAR();

    // ---- main loop: t = 0,2,...,60 (31 iterations) ----
    for (int i = 0; i < 31; ++i) {
        const int t = 2 * i;
        // ph1
        RD_A(aX, 0, 0); RD_B(bX, 0, 0);
        STG_A(1, 1, t + 1);
        LGK8();
        BAR(); LGK0();
        MM(0, 0, aX, bX);
        BAR();
        // ph2
        RD_B(bY, 0, 1);
        STG_A(0, 0, t + 2);
        BAR(); LGK0();
        MM(0, 1, aX, bY);
        BAR();
        // ph3
        RD_A(aY, 0, 1);
        STG_B(0, 0, t + 2);
        BAR(); LGK0();
        MM(1, 1, aY, bY);
        BAR();
        // ph4
        STG_B(0, 1, t + 2);
        BAR();
        MM(1, 0, aY, bX);
        VMC(6);
        BAR();
        // ph5
        RD_A(aX, 1, 0); RD_B(bX, 1, 0);
        STG_A(0, 1, t + 2);
        LGK8();
        BAR(); LGK0();
        MM(0, 0, aX, bX);
        BAR();
        // ph6
        RD_B(bY, 1, 1);
        STG_A(1, 0, t + 3);
        BAR(); LGK0();
        MM(0, 1, aX, bY);
        BAR();
        // ph7
        RD_A(aY, 1, 1);
        STG_B(1, 0, t + 3);
        BAR(); LGK0();
        MM(1, 1, aY, bY);
        BAR();
        // ph8
        STG_B(1, 1, t + 3);
        BAR();
        MM(1, 0, aY, bX);
        VMC(6);
        BAR();
    }

    // ---- epilogue: tiles 62 (buf0), 63 (buf1) ----
    // ph1
    RD_A(aX, 0, 0); RD_B(bX, 0, 0);
    STG_A(1, 1, 63);
    BAR(); LGK0();
    MM(0, 0, aX, bX);
    BAR();
    // ph2
    RD_B(bY, 0, 1);
    BAR(); LGK0();
    MM(0, 1, aX, bY);
    BAR();
    // ph3
    RD_A(aY, 0, 1);
    BAR(); LGK0();
    MM(1, 1, aY, bY);
    BAR();
    // ph4
    MM(1, 0, aY, bX);
    VMC(0);
    BAR();
    // ph5-8 (tile 63, fully resident)
    RD_A(aX, 1, 0); RD_B(bX, 1, 0);
    BAR(); LGK0();
    MM(0, 0, aX, bX);
    BAR();
    RD_B(bY, 1, 1);
    BAR(); LGK0();
    MM(0, 1, aX, bY);
    BAR();
    RD_A(aY, 1, 1);
    BAR(); LGK0();
    MM(1, 1, aY, bY);
    MM(1, 0, aY, bX);

    // ---- C write: 16x16 layout col = lane&15, row = (lane>>4)*4 + reg ----
    const size_t crow = (size_t)(bm * 256 + wm * 128 + hi * 4);
    const int    ccol = bn * 256 + wn * 64 + fr;
#pragma unroll
    for (int mi = 0; mi < 8; ++mi)
#pragma unroll
        for (int ni = 0; ni < 4; ++ni) {
            const size_t row = crow + mi * 16;
            const int    col = ccol + ni * 16;
#pragma unroll
            for (int r = 0; r < 4; ++r)
                C[(row + r) * Ndim + col] = acc[mi][ni][r];
        }

#undef STG_A
#undef STG_B
#undef RD_A
#undef RD_B
#undef MM
}

// ---------------------------------------------------------------------------
// Fallback if workspace too small: plain f32 tiles
// ---------------------------------------------------------------------------
__global__ void gemm_f32_naive(const float* __restrict__ A, const float* __restrict__ B,
                               float* __restrict__ C) {
    __shared__ float As[32][33], Bs[32][33];
    const int tx = threadIdx.x & 31, ty = threadIdx.x >> 5;
    const int row0 = blockIdx.y * 32, col0 = blockIdx.x * 32;
    float acc[4] = {0.f, 0.f, 0.f, 0.f};
    for (int k0 = 0; k0 < Kdim; k0 += 32) {
        for (int i = threadIdx.x; i < 32 * 32; i += 256) {
            int r = i >> 5, c = i & 31;
            As[r][c] = A[(size_t)(row0 + r) * Kdim + k0 + c];
            Bs[r][c] = B[(size_t)(k0 + r) * Ndim + col0 + c];
        }
        __syncthreads();
#pragma unroll 8
        for (int kk = 0; kk < 32; ++kk) {
            float bv = Bs[kk][tx];
#pragma unroll
            for (int i = 0; i < 4; ++i) acc[i] += As[ty + 8 * i][kk] * bv;
        }
        __syncthreads();
    }
#pragma unroll
    for (int i = 0; i < 4; ++i)
        C[(size_t)(row0 + ty + 8 * i) * Ndim + col0 + tx] = acc[i];
}

extern "C" void kernel_launch(void* const* d_in, const int* in_sizes, int n_in,
                              void* d_out, int out_size, void* d_ws, size_t ws_size,
                              hipStream_t stream) {
    const float* x = (const float*)d_in[0];
    const float* y = (const float*)d_in[1];
    float* out = (float*)d_out;

    const size_t elemsA = (size_t)Mdim * Kdim;
    const size_t elemsB = (size_t)Ndim * Kdim;
    const size_t need   = (elemsA + elemsB) * sizeof(unsigned short);  // 64 MiB

    if (ws_size >= need) {
        unsigned short* Apk = (unsigned short*)d_ws;
        unsigned short* Bpk = Apk + elemsA;

        conv_a_pack<<<dim3(Kdim / 64, Mdim / 64), 256, 0, stream>>>(x, Apk);
        conv_b_pack<<<dim3(Kdim / 64, Ndim / 64), 256, 0, stream>>>(y, Bpk);
        gemm8k<<<dim3((Mdim / 256) * (Ndim / 256)), 512, 0, stream>>>(Apk, Bpk, out);
    } else {
        gemm_f32_naive<<<dim3(Ndim / 32, Mdim / 32), 256, 0, stream>>>(x, y, out);
    }
}

// Round 10
// 149.062 us; speedup vs baseline: 1.0039x; 1.0039x over previous
//
#include <hip/hip_runtime.h>
#include <stdint.h>

#define Mdim 4096
#define Kdim 4096
#define Ndim 4096

typedef __attribute__((ext_vector_type(8))) short bf16x8;   // 8 bf16 (MFMA A/B frag)
typedef __attribute__((ext_vector_type(4))) float f32x4;    // 16x16 MFMA C/D frag

static __device__ __forceinline__ unsigned short f2bf_rne(float f) {
    union { float f; unsigned u; } v; v.f = f;
    unsigned u = v.u;
    u += 0x7FFFu + ((u >> 16) & 1u);
    return (unsigned short)(u >> 16);
}

static __device__ __forceinline__ void gload_lds16(const unsigned short* g, unsigned short* l) {
    __builtin_amdgcn_global_load_lds(
        (const __attribute__((address_space(1))) unsigned int*)g,
        (__attribute__((address_space(3))) unsigned int*)l,
        16, 0, 0);
}

#define BAR()   do { asm volatile("" ::: "memory"); __builtin_amdgcn_s_barrier(); asm volatile("" ::: "memory"); } while (0)
#define VMC(N)  asm volatile("s_waitcnt vmcnt(" #N ")" ::: "memory")
#define LGK8()  asm volatile("s_waitcnt lgkmcnt(8)" ::: "memory")
// NOTE (r10): no lgkmcnt(0) before MFMA blocks. The ds_reads are
// compiler-visible loads, so the compiler emits fine-grained COUNTED
// lgkmcnt per MFMA operand (m97 asm evidence) -> first MFMA starts when its
// own reads land, tail reads drain UNDER the MFMA sequence. r9's explicit
// lgkmcnt(0)+sched_barrier forced a full drain before any MFMA (the measured
// 576-cyc serial LDS tail = the plateau).

// ---------------------------------------------------------------------------
// Packing kernels: f32 -> bf16, k-major 16B-unit layout.
// A_p[(kt*8+o)*4096 + row] = A[row][kt*64+o*8 .. +8]
// B_p[(kt*8+o)*4096 + col] = B[kt*64+o*8 .. +8][col]   (B^T, k-major)
// ---------------------------------------------------------------------------
__global__ void conv_a_pack(const float* __restrict__ a, unsigned short* __restrict__ out) {
    __shared__ float tile[64][65];
    const int kt = blockIdx.x, rt = blockIdx.y;
    for (int i = threadIdx.x; i < 64 * 64; i += 256) {
        int r = i >> 6, c = i & 63;
        tile[r][c] = a[(size_t)(rt * 64 + r) * Kdim + kt * 64 + c];
    }
    __syncthreads();
    for (int i = threadIdx.x; i < 512; i += 256) {
        int o = i >> 6, r = i & 63;
        bf16x8 v;
#pragma unroll
        for (int e = 0; e < 8; ++e) v[e] = (short)f2bf_rne(tile[r][o * 8 + e]);
        ((bf16x8*)out)[(size_t)(kt * 8 + o) * 4096 + rt * 64 + r] = v;
    }
}

__global__ void conv_b_pack(const float* __restrict__ b, unsigned short* __restrict__ out) {
    __shared__ float tile[64][65];
    const int kt = blockIdx.x, nt = blockIdx.y;
    for (int i = threadIdx.x; i < 64 * 64; i += 256) {
        int kk = i >> 6, n = i & 63;
        tile[kk][n] = b[(size_t)(kt * 64 + kk) * Ndim + nt * 64 + n];
    }
    __syncthreads();
    for (int i = threadIdx.x; i < 512; i += 256) {
        int o = i >> 6, n = i & 63;
        bf16x8 v;
#pragma unroll
        for (int e = 0; e < 8; ++e) v[e] = (short)f2bf_rne(tile[o * 8 + e][n]);
        ((bf16x8*)out)[(size_t)(kt * 8 + o) * 4096 + nt * 64 + n] = v;
    }
}

// ---------------------------------------------------------------------------
// 256x256 bf16 GEMM, 16x16x32 MFMA, 8-phase schedule + k-major LDS.
// Identical to round-9 gemm8k EXCEPT: no lgkmcnt(0)/sched_barrier pinning
// before MFMA blocks (compiler emits counted lgkm waits -> LDS drain hides
// under MFMA). VMC(6)/VMC(0) counted retires kept (gload_lds->ds_read RAW is
// compiler-invisible); raw barriers kept; LGK8 smoothing kept; setprio kept.
// WAR: every read completes before its phase's last dependent MFMA (in-order
// DS + per-operand waits), which precedes the barrier preceding any
// overwriting stage. RAW: VMC retire + barrier before reads of a new tile.
// ---------------------------------------------------------------------------
__global__ __launch_bounds__(512, 2) void gemm8k(const unsigned short* __restrict__ Ap,
                                                 const unsigned short* __restrict__ Bp,
                                                 float* __restrict__ C) {
    __shared__ unsigned short lds[65536];  // 128 KiB

    const int lane = threadIdx.x & 63;
    const int w    = threadIdx.x >> 6;   // 0..7
    const int wm   = w >> 2;             // 0..1
    const int wn   = w & 3;              // 0..3

    // bijective XCD swizzle (gridDim.x = 256)
    const int nch = gridDim.x >> 3;
    const int swz = (blockIdx.x & 7) * nch + (blockIdx.x >> 3);
    const int bm  = swz >> 4;
    const int bn  = swz & 15;

    // ---- staging geometry: wave w, instr j covers slab s_j, p = par*64+lane ----
    const int par = w & 1;
    const int s0  = w >> 1;              // j=0 slab; j=1 slab = s0+4
    const int aB  = bm * 256 + par * 128 + lane;                           // + MH*64
    const int bB  = bn * 256 + (par * 2 + (lane >> 5)) * 64 + (lane & 31); // + NH*32

#define STG_A(Q, MH, T) do {                                                     \
        unsigned short* d_ = lds + (Q) * 32768 + (MH) * 8192 + w * 512;          \
        gload_lds16(Ap + 8 * ((size_t)(T) * 32768 + s0 * 4096 + aB + (MH) * 64), \
                    d_);                                                         \
        gload_lds16(Ap + 8 * ((size_t)(T) * 32768 + (s0 + 4) * 4096 + aB + (MH) * 64), \
                    d_ + 4096);                                                  \
    } while (0)
#define STG_B(Q, NH, T) do {                                                     \
        unsigned short* d_ = lds + (Q) * 32768 + 16384 + (NH) * 8192 + w * 512;  \
        gload_lds16(Bp + 8 * ((size_t)(T) * 32768 + s0 * 4096 + bB + (NH) * 32), \
                    d_);                                                         \
        gload_lds16(Bp + 8 * ((size_t)(T) * 32768 + (s0 + 4) * 4096 + bB + (NH) * 32), \
                    d_ + 4096);                                                  \
    } while (0)

    // ---- fragment reads: addr = P*64K + [A: MH*16K | B: 32K+NH*16K]
    //      + (kk*4+hi)*2048 + p*16 ----
    const int fr = lane & 15;
    const int hi = lane >> 4;
    const char* ldsc = (const char*)lds;
    const int rdA = (wm * 64 + fr) * 16 + hi * 2048;   // + m*256 + kk*8192
    const int rdB = (wn * 32 + fr) * 16 + hi * 2048;   // + n'*256 + kk*8192

#define RD_A(DST, P, MH) do { _Pragma("unroll")                                  \
        for (int m_ = 0; m_ < 4; ++m_) {                                         \
            DST[m_][0] = *(const bf16x8*)(ldsc + (P) * 65536 + (MH) * 16384 +    \
                                          rdA + m_ * 256);                       \
            DST[m_][1] = *(const bf16x8*)(ldsc + (P) * 65536 + (MH) * 16384 +    \
                                          rdA + m_ * 256 + 8192);                \
        } } while (0)
#define RD_B(DST, P, NH) do { _Pragma("unroll")                                  \
        for (int n_ = 0; n_ < 2; ++n_) {                                         \
            DST[n_][0] = *(const bf16x8*)(ldsc + (P) * 65536 + 32768 +           \
                                          (NH) * 16384 + rdB + n_ * 256);        \
            DST[n_][1] = *(const bf16x8*)(ldsc + (P) * 65536 + 32768 +           \
                                          (NH) * 16384 + rdB + n_ * 256 + 8192); \
        } } while (0)

#define MM(MH, NH, AF, BF) do {                                                  \
        __builtin_amdgcn_s_setprio(1);                                           \
        _Pragma("unroll")                                                        \
        for (int m_ = 0; m_ < 4; ++m_)                                           \
            _Pragma("unroll")                                                    \
            for (int n_ = 0; n_ < 2; ++n_) {                                     \
                acc[(MH)*4 + m_][(NH)*2 + n_] = __builtin_amdgcn_mfma_f32_16x16x32_bf16( \
                    AF[m_][0], BF[n_][0], acc[(MH)*4 + m_][(NH)*2 + n_], 0, 0, 0); \
                acc[(MH)*4 + m_][(NH)*2 + n_] = __builtin_amdgcn_mfma_f32_16x16x32_bf16( \
                    AF[m_][1], BF[n_][1], acc[(MH)*4 + m_][(NH)*2 + n_], 0, 0, 0); \
            }                                                                    \
        __builtin_amdgcn_s_setprio(0);                                           \
    } while (0)

    f32x4 acc[8][4] = {};
    bf16x8 aX[4][2], aY[4][2], bX[2][2], bY[2][2];

    // ---- prologue: buf0(tile0) 4 halves + buf1(tile1) 3 halves; retire t0 ----
    STG_A(0, 0, 0); STG_B(0, 0, 0); STG_B(0, 1, 0); STG_A(0, 1, 0);
    STG_A(1, 0, 1); STG_B(1, 0, 1); STG_B(1, 1, 1);
    VMC(6);  // 3 halves outstanding -> all of tile 0 landed
    BAR();

    // ---- main loop: t = 0,2,...,60 (31 iterations) ----
    for (int i = 0; i < 31; ++i) {
        const int t = 2 * i;
        // ph1
        RD_A(aX, 0, 0); RD_B(bX, 0, 0);
        STG_A(1, 1, t + 1);
        LGK8();
        BAR();
        MM(0, 0, aX, bX);
        BAR();
        // ph2
        RD_B(bY, 0, 1);
        STG_A(0, 0, t + 2);
        BAR();
        MM(0, 1, aX, bY);
        BAR();
        // ph3
        RD_A(aY, 0, 1);
        STG_B(0, 0, t + 2);
        BAR();
        MM(1, 1, aY, bY);
        BAR();
        // ph4
        STG_B(0, 1, t + 2);
        BAR();
        MM(1, 0, aY, bX);
        VMC(6);
        BAR();
        // ph5
        RD_A(aX, 1, 0); RD_B(bX, 1, 0);
        STG_A(0, 1, t + 2);
        LGK8();
        BAR();
        MM(0, 0, aX, bX);
        BAR();
        // ph6
        RD_B(bY, 1, 1);
        STG_A(1, 0, t + 3);
        BAR();
        MM(0, 1, aX, bY);
        BAR();
        // ph7
        RD_A(aY, 1, 1);
        STG_B(1, 0, t + 3);
        BAR();
        MM(1, 1, aY, bY);
        BAR();
        // ph8
        STG_B(1, 1, t + 3);
        BAR();
        MM(1, 0, aY, bX);
        VMC(6);
        BAR();
    }

    // ---- epilogue: tiles 62 (buf0), 63 (buf1) ----
    RD_A(aX, 0, 0); RD_B(bX, 0, 0);
    STG_A(1, 1, 63);
    BAR();
    MM(0, 0, aX, bX);
    BAR();
    RD_B(bY, 0, 1);
    BAR();
    MM(0, 1, aX, bY);
    BAR();
    RD_A(aY, 0, 1);
    BAR();
    MM(1, 1, aY, bY);
    BAR();
    MM(1, 0, aY, bX);
    VMC(0);
    BAR();
    RD_A(aX, 1, 0); RD_B(bX, 1, 0);
    BAR();
    MM(0, 0, aX, bX);
    BAR();
    RD_B(bY, 1, 1);
    BAR();
    MM(0, 1, aX, bY);
    BAR();
    RD_A(aY, 1, 1);
    BAR();
    MM(1, 1, aY, bY);
    MM(1, 0, aY, bX);

    // ---- C write: 16x16 layout col = lane&15, row = (lane>>4)*4 + reg ----
    const size_t crow = (size_t)(bm * 256 + wm * 128 + hi * 4);
    const int    ccol = bn * 256 + wn * 64 + fr;
#pragma unroll
    for (int mi = 0; mi < 8; ++mi)
#pragma unroll
        for (int ni = 0; ni < 4; ++ni) {
            const size_t row = crow + mi * 16;
            const int    col = ccol + ni * 16;
#pragma unroll
            for (int r = 0; r < 4; ++r)
                C[(row + r) * Ndim + col] = acc[mi][ni][r];
        }

#undef STG_A
#undef STG_B
#undef RD_A
#undef RD_B
#undef MM
}

// ---------------------------------------------------------------------------
// Fallback if workspace too small: plain f32 tiles
// ---------------------------------------------------------------------------
__global__ void gemm_f32_naive(const float* __restrict__ A, const float* __restrict__ B,
                               float* __restrict__ C) {
    __shared__ float As[32][33], Bs[32][33];
    const int tx = threadIdx.x & 31, ty = threadIdx.x >> 5;
    const int row0 = blockIdx.y * 32, col0 = blockIdx.x * 32;
    float acc[4] = {0.f, 0.f, 0.f, 0.f};
    for (int k0 = 0; k0 < Kdim; k0 += 32) {
        for (int i = threadIdx.x; i < 32 * 32; i += 256) {
            int r = i >> 5, c = i & 31;
            As[r][c] = A[(size_t)(row0 + r) * Kdim + k0 + c];
            Bs[r][c] = B[(size_t)(k0 + r) * Ndim + col0 + c];
        }
        __syncthreads();
#pragma unroll 8
        for (int kk = 0; kk < 32; ++kk) {
            float bv = Bs[kk][tx];
#pragma unroll
            for (int i = 0; i < 4; ++i) acc[i] += As[ty + 8 * i][kk] * bv;
        }
        __syncthreads();
    }
#pragma unroll
    for (int i = 0; i < 4; ++i)
        C[(size_t)(row0 + ty + 8 * i) * Ndim + col0 + tx] = acc[i];
}

extern "C" void kernel_launch(void* const* d_in, const int* in_sizes, int n_in,
                              void* d_out, int out_size, void* d_ws, size_t ws_size,
                              hipStream_t stream) {
    const float* x = (const float*)d_in[0];
    const float* y = (const float*)d_in[1];
    float* out = (float*)d_out;

    const size_t elemsA = (size_t)Mdim * Kdim;
    const size_t elemsB = (size_t)Ndim * Kdim;
    const size_t need   = (elemsA + elemsB) * sizeof(unsigned short);  // 64 MiB

    if (ws_size >= need) {
        unsigned short* Apk = (unsigned short*)d_ws;
        unsigned short* Bpk = Apk + elemsA;

        conv_a_pack<<<dim3(Kdim / 64, Mdim / 64), 256, 0, stream>>>(x, Apk);
        conv_b_pack<<<dim3(Kdim / 64, Ndim / 64), 256, 0, stream>>>(y, Bpk);
        gemm8k<<<dim3((Mdim / 256) * (Ndim / 256)), 512, 0, stream>>>(Apk, Bpk, out);
    } else {
        gemm_f32_naive<<<dim3(Ndim / 32, Mdim / 32), 256, 0, stream>>>(x, y, out);
    }
}